// Round 3
// baseline (924.934 us; speedup 1.0000x reference)
//
#include <hip/hip_runtime.h>
#include <math.h>

// Problem constants (fixed by the reference)
#define Bdim 1024
#define DEPTHC 6

typedef __attribute__((ext_vector_type(8))) short bf16x8;
typedef __attribute__((ext_vector_type(4))) float f32x4;

__device__ __forceinline__ unsigned short f2bf(float x) {
    unsigned u = __float_as_uint(x);
    u += 0x7fffu + ((u >> 16) & 1u);
    return (unsigned short)(u >> 16);
}
__device__ __forceinline__ float bf2f(unsigned short h) {
    return __uint_as_float(((unsigned)h) << 16);
}
__device__ __forceinline__ float sigmf(float x) { return 1.0f / (1.0f + expf(-x)); }

__device__ __forceinline__ void glds16(const void* g, void* l) {
    __builtin_amdgcn_global_load_lds(
        (const __attribute__((address_space(1))) unsigned int*)g,
        (__attribute__((address_space(3))) unsigned int*)l, 16, 0, 0);
}

// Preorder index of node (level, q) in a full binary tree of depth DEPTHC.
__device__ __forceinline__ int preorder_idx(int level, int q) {
    int idx = 0, rem = DEPTHC;
    for (int k = level - 1; k >= 0; --k) {
        int b = (q >> k) & 1;
        idx += 1 + b * ((1 << (rem - 1)) - 1);
        rem--;
    }
    return idx;
}

// ---------------------------------------------------------------------------
// fp32 -> bf16x2 split converter: dst[r][0:k]=hi, dst[r][k:2k]=lo
// ---------------------------------------------------------------------------
struct CvtEnt { const float* src; unsigned short* dst; int n; int klog2; };
struct CvtArgs { CvtEnt e[10]; };

__global__ __launch_bounds__(256) void cvt_bf16x2(CvtArgs a) {
    CvtEnt E = a.e[blockIdx.y];
    const int k = 1 << E.klog2;
    for (int t = blockIdx.x * 256 + threadIdx.x; t < E.n; t += gridDim.x * 256) {
        const float x = E.src[t];
        const int r = t >> E.klog2, c = t & (k - 1);
        const unsigned short hi = f2bf(x);
        unsigned short* d = E.dst + ((size_t)r << (E.klog2 + 1));
        d[c] = hi;
        d[k + c] = f2bf(x - bf2f(hi));
    }
}

// ---------------------------------------------------------------------------
// Shared 128x128 K=256(bf16x2, 12-step split) main loop, 2-phase dbuf LDS.
// As/Ws: 2 x 8192 shorts each. acc[4][4] f32x4.
// ---------------------------------------------------------------------------
__device__ __forceinline__ void gemm128_body(
    const unsigned short* __restrict__ A2, int arow0,
    const unsigned short* __restrict__ W2, int wrow0,
    unsigned short* As, unsigned short* Ws, f32x4 acc[4][4])
{
    const int tid = threadIdx.x;
    const int w = tid >> 6, lane = tid & 63;
    const int srow = (w << 5) + (lane >> 3);
    const int sslot = lane & 7;
    const int wm = (w >> 1) << 6, wn = (w & 1) << 6;

    #pragma unroll
    for (int i = 0; i < 4; ++i)
        #pragma unroll
        for (int j = 0; j < 4; ++j)
            #pragma unroll
            for (int r = 0; r < 4; ++r) acc[i][j][r] = 0.f;

    auto stage = [&](int buf, int s) {
        const int ka = ((s & 3) << 6) + (((unsigned)(s - 4) < 4u) ? 256 : 0);
        const int kw = ((s & 3) << 6) + ((s >= 8) ? 256 : 0);
        #pragma unroll
        for (int i = 0; i < 4; ++i) {
            const int r = srow + (i << 3);
            const int sl = sslot ^ (r & 7);
            glds16(A2 + (size_t)(arow0 + r) * 512 + ka + (sl << 3),
                   As + buf * 8192 + (w << 11) + (i << 9));
            glds16(W2 + (size_t)(wrow0 + r) * 512 + kw + (sl << 3),
                   Ws + buf * 8192 + (w << 11) + (i << 9));
        }
    };
    auto compute = [&](int buf) {
        #pragma unroll
        for (int kk = 0; kk < 2; ++kk) {
            bf16x8 af[4], bw[4];
            #pragma unroll
            for (int mf = 0; mf < 4; ++mf) {
                const int row = wm + (mf << 4) + (lane & 15);
                const int sl = (((kk << 2) | (lane >> 4)) ^ (row & 7)) << 3;
                af[mf] = *(const bf16x8*)&As[buf * 8192 + (row << 6) + sl];
            }
            #pragma unroll
            for (int nf = 0; nf < 4; ++nf) {
                const int row = wn + (nf << 4) + (lane & 15);
                const int sl = (((kk << 2) | (lane >> 4)) ^ (row & 7)) << 3;
                bw[nf] = *(const bf16x8*)&Ws[buf * 8192 + (row << 6) + sl];
            }
            #pragma unroll
            for (int mf = 0; mf < 4; ++mf)
                #pragma unroll
                for (int nf = 0; nf < 4; ++nf)
                    acc[mf][nf] = __builtin_amdgcn_mfma_f32_16x16x32_bf16(
                        af[mf], bw[nf], acc[mf][nf], 0, 0, 0);
        }
    };

    stage(0, 0);
    #pragma unroll
    for (int s = 0; s < 12; ++s) {
        __syncthreads();
        if (s + 1 < 12) stage((s + 1) & 1, s + 1);
        compute(s & 1);
    }
}

// ---------------------------------------------------------------------------
// Generic GEMM: C = A @ W^T + bias. Grid: (N/128, M/128) col-fast.
// Output row m -> node p=m>>10, out row = (p*outStride+outOffset)*1024+(m&1023).
// ---------------------------------------------------------------------------
__global__ __launch_bounds__(256) void mfma_gemm(
    const unsigned short* __restrict__ A2, const unsigned short* __restrict__ W2,
    const float* __restrict__ bias, float* __restrict__ Cf, int Nf,
    unsigned short* __restrict__ C2, int outStride, int outOffset)
{
    __shared__ __attribute__((aligned(16))) unsigned short As[16384];
    __shared__ __attribute__((aligned(16))) unsigned short Ws[16384];

    const int tid = threadIdx.x;
    const int w = tid >> 6, lane = tid & 63;
    const int col0 = blockIdx.x * 128, m0 = blockIdx.y * 128;
    const int p = m0 >> 10;
    const int wm = (w >> 1) << 6, wn = (w & 1) << 6;

    f32x4 acc[4][4];
    gemm128_body(A2, m0, W2, col0, As, Ws, acc);

    const size_t oBase = (((size_t)(p * outStride + outOffset)) << 10) + (m0 & 1023);
    #pragma unroll
    for (int nf = 0; nf < 4; ++nf) {
        const int col = col0 + wn + (nf << 4) + (lane & 15);
        const float bj = bias[col];
        #pragma unroll
        for (int mf = 0; mf < 4; ++mf) {
            const int rb = wm + (mf << 4) + ((lane >> 4) << 2);
            #pragma unroll
            for (int r = 0; r < 4; ++r) {
                const float v = acc[mf][nf][r] + bj;
                const size_t orow = oBase + rb + r;
                if (Cf) Cf[orow * (size_t)Nf + col] = v;
                if (C2) {
                    const unsigned short hi = f2bf(v);
                    C2[orow * 512 + col] = hi;
                    C2[orow * 512 + 256 + col] = f2bf(v - bf2f(hi));
                }
            }
        }
    }
}

// ---------------------------------------------------------------------------
// Dual GEMM over concatenated weights [ga_wh(768) | w_c_w(256)] -> N=1024.
// cols <768: GhA (fp32, +ga_bh). cols >=768: hac' (fp32 + bf16x2, +w_c_b).
// Grid (8, 8). A = hac2 (1024 rows).
// ---------------------------------------------------------------------------
__global__ __launch_bounds__(256) void mfma_gemm_dual(
    const unsigned short* __restrict__ A2, const unsigned short* __restrict__ Wcat,
    const float* __restrict__ bias_g, const float* __restrict__ bias_c,
    float* __restrict__ GhA, float* __restrict__ hacF, unsigned short* __restrict__ hac2)
{
    __shared__ __attribute__((aligned(16))) unsigned short As[16384];
    __shared__ __attribute__((aligned(16))) unsigned short Ws[16384];

    const int tid = threadIdx.x;
    const int w = tid >> 6, lane = tid & 63;
    const int col0 = blockIdx.x * 128, m0 = blockIdx.y * 128;
    const int wm = (w >> 1) << 6, wn = (w & 1) << 6;

    f32x4 acc[4][4];
    gemm128_body(A2, m0, Wcat, col0, As, Ws, acc);

    #pragma unroll
    for (int nf = 0; nf < 4; ++nf) {
        const int col = col0 + wn + (nf << 4) + (lane & 15);
        #pragma unroll
        for (int mf = 0; mf < 4; ++mf) {
            const int rb = m0 + wm + (mf << 4) + ((lane >> 4) << 2);
            #pragma unroll
            for (int r = 0; r < 4; ++r) {
                const size_t orow = rb + r;
                if (col0 < 768) {
                    GhA[orow * 768 + col] = acc[mf][nf][r] + bias_g[col];
                } else {
                    const int c = col - 768;
                    const float v = acc[mf][nf][r] + bias_c[c];
                    hacF[orow * 256 + c] = v;
                    const unsigned short hi = f2bf(v);
                    hac2[orow * 512 + c] = hi;
                    hac2[orow * 512 + 256 + c] = f2bf(v - bf2f(hi));
                }
            }
        }
    }
}

// ---------------------------------------------------------------------------
// pred = H @ h2o^T + b (MFMA, bf16x2 split, direct-from-global fragments),
// scatter to out at preorder index; softmax -> SP2 (bf16x2 [slot][1024][64]).
// Block: 128 rows of one node. Grid: M/128 (stripe = p*8 + sub).
// ---------------------------------------------------------------------------
__global__ __launch_bounds__(256) void pred_softmax_mfma(
    const unsigned short* __restrict__ A2, const unsigned short* __restrict__ h2o2,
    const float* __restrict__ h2o_b, float* __restrict__ out,
    unsigned short* __restrict__ SP2, int level, int nodeStride, int nodeOffset)
{
    const int tid = threadIdx.x;
    const int w = tid >> 6, lane = tid & 63;
    const int stripe = blockIdx.x;
    const int p = stripe >> 3;
    const int q = p * nodeStride + nodeOffset;
    const int b0 = (stripe & 7) * 128;
    const size_t abase = ((size_t)q << 10) + b0;

    f32x4 acc[2][2];
    #pragma unroll
    for (int i = 0; i < 2; ++i)
        #pragma unroll
        for (int j = 0; j < 2; ++j)
            #pragma unroll
            for (int r = 0; r < 4; ++r) acc[i][j][r] = 0.f;

    #pragma unroll
    for (int s = 0; s < 12; ++s) {
        const int ka = ((s & 3) << 6) + (((unsigned)(s - 4) < 4u) ? 256 : 0);
        const int kw = ((s & 3) << 6) + ((s >= 8) ? 256 : 0);
        #pragma unroll
        for (int kk = 0; kk < 2; ++kk) {
            const int ko = (kk << 5) + ((lane >> 4) << 3);
            bf16x8 af[2], bw[2];
            #pragma unroll
            for (int mf = 0; mf < 2; ++mf) {
                const size_t row = abase + (w << 5) + (mf << 4) + (lane & 15);
                af[mf] = *(const bf16x8*)(A2 + row * 512 + ka + ko);
            }
            #pragma unroll
            for (int nf = 0; nf < 2; ++nf) {
                const int col = (nf << 4) + (lane & 15);
                bw[nf] = *(const bf16x8*)(h2o2 + (size_t)col * 512 + kw + ko);
            }
            #pragma unroll
            for (int mf = 0; mf < 2; ++mf)
                #pragma unroll
                for (int nf = 0; nf < 2; ++nf)
                    acc[mf][nf] = __builtin_amdgcn_mfma_f32_16x16x32_bf16(
                        af[mf], bw[nf], acc[mf][nf], 0, 0, 0);
        }
    }

    const int idx = preorder_idx(level, q);
    const float bj0 = h2o_b[(lane & 15)];
    const float bj1 = h2o_b[16 + (lane & 15)];

    #pragma unroll
    for (int mf = 0; mf < 2; ++mf) {
        #pragma unroll
        for (int r = 0; r < 4; ++r) {
            const int b = b0 + (w << 5) + (mf << 4) + ((lane >> 4) << 2) + r;
            const float v0 = acc[mf][0][r] + bj0;
            const float v1 = acc[mf][1][r] + bj1;
            // write pred
            const size_t obase = (((size_t)idx << 10) + b) * 32;
            out[obase + (lane & 15)] = v0;
            out[obase + 16 + (lane & 15)] = v1;
            // softmax over 32 cols (16 lanes x 2 frags)
            float mx = fmaxf(v0, v1);
            #pragma unroll
            for (int off = 8; off > 0; off >>= 1) mx = fmaxf(mx, __shfl_xor(mx, off, 64));
            const float e0 = expf(v0 - mx), e1 = expf(v1 - mx);
            float sum = e0 + e1;
            #pragma unroll
            for (int off = 8; off > 0; off >>= 1) sum += __shfl_xor(sum, off, 64);
            const float inv = 1.0f / sum;
            const float s0 = e0 * inv, s1 = e1 * inv;
            const size_t sbase = (((size_t)q << 10) + b) * 64;
            const unsigned short h0 = f2bf(s0), h1 = f2bf(s1);
            SP2[sbase + (lane & 15)] = h0;
            SP2[sbase + 16 + (lane & 15)] = h1;
            SP2[sbase + 32 + (lane & 15)] = f2bf(s0 - bf2f(h0));
            SP2[sbase + 48 + (lane & 15)] = f2bf(s1 - bf2f(h1));
        }
    }
}

// ---------------------------------------------------------------------------
// Fused fraternal+ancestral GRU:
//   hf' = GRU_s(spf, hf)  [h-path 12 split steps, x-path 1 diag step]
//   ap  = GRU_a(sp_parent, hac)  [x-path 1 diag step; h-part from GhA]
//   hidden2 = hf' + ap  -> Ap2 (bf16x2)
// BM=64, 64 gate-cols per block. Grid (4, M/64). 2-phase dbuf.
// ---------------------------------------------------------------------------
__global__ __launch_bounds__(256) void gru_s_fused(
    const unsigned short* __restrict__ Hn2,   // l+1 arena (first children, slots 2p)
    const unsigned short* __restrict__ SP2n,  // l+1 SP arena (slots 2p)
    const unsigned short* __restrict__ SP2c,  // level-l SP arena (rows = m)
    const unsigned short* __restrict__ gsW2, const unsigned short* __restrict__ gsX2,
    const unsigned short* __restrict__ gaX2,
    const float* __restrict__ gs_bx, const float* __restrict__ gs_bh,
    const float* __restrict__ ga_bx,
    const float* __restrict__ GhA, const float* __restrict__ haF,
    unsigned short* __restrict__ Ap2)
{
    __shared__ __attribute__((aligned(16))) unsigned short As[2][4096];   // 64x64
    __shared__ __attribute__((aligned(16))) unsigned short Ws[2][12288];  // 192x64

    const int tid = threadIdx.x;
    const int w = tid >> 6, lane = tid & 63;
    const int col0 = blockIdx.x * 64;
    const int m0 = blockIdx.y * 64;
    const int p = m0 >> 10;
    const size_t aBase = (((size_t)(2 * p)) << 10) + (m0 & 1023);
    const int wr = w >> 1, wc = w & 1;

    f32x4 a_sr[2][2] = {}, a_sz[2][2] = {}, a_snh[2][2] = {}, a_snx[2][2] = {};
    f32x4 a_ar[2][2] = {}, a_az[2][2] = {}, a_an[2][2] = {};

    auto stage = [&](int buf, int s) {
        #pragma unroll
        for (int i = 0; i < 2; ++i) {
            const int r = (w << 4) + (i << 3) + (lane >> 3);
            const int sl = (lane & 7) ^ (r & 7);
            const unsigned short* src;
            if (s < 12) {
                const int ka = ((s & 3) << 6) + (((unsigned)(s - 4) < 4u) ? 256 : 0);
                src = Hn2 + (aBase + r) * 512 + ka + (sl << 3);
            } else if (s == 12) {
                src = SP2n + (aBase + r) * 64 + (sl << 3);
            } else {
                src = SP2c + (size_t)(m0 + r) * 64 + (sl << 3);
            }
            glds16(src, &As[buf][(w << 10) + (i << 9)]);
        }
        #pragma unroll
        for (int j = 0; j < 6; ++j) {
            const int R = w * 48 + (j << 3) + (lane >> 3);
            const int g = R >> 6, c = R & 63;
            const int sl = (lane & 7) ^ (R & 7);
            const size_t grow = (size_t)(g * 256 + col0 + c);
            const unsigned short* src;
            if (s < 12) {
                const int kw = ((s & 3) << 6) + ((s >= 8) ? 256 : 0);
                src = gsW2 + grow * 512 + kw + (sl << 3);
            } else if (s == 12) {
                src = gsX2 + grow * 64 + (sl << 3);
            } else {
                src = gaX2 + grow * 64 + (sl << 3);
            }
            glds16(src, &Ws[buf][(w * 48 + (j << 3)) << 6]);
        }
    };

    auto compute = [&](int buf, f32x4 (*tr)[2], f32x4 (*tz)[2], f32x4 (*tn)[2]) {
        #pragma unroll
        for (int kk = 0; kk < 2; ++kk) {
            bf16x8 af[2], bw[3][2];
            #pragma unroll
            for (int mf = 0; mf < 2; ++mf) {
                const int row = (wr << 5) + (mf << 4) + (lane & 15);
                const int sl = (((kk << 2) | (lane >> 4)) ^ (row & 7)) << 3;
                af[mf] = *(const bf16x8*)&As[buf][(row << 6) + sl];
            }
            #pragma unroll
            for (int g = 0; g < 3; ++g)
                #pragma unroll
                for (int nf = 0; nf < 2; ++nf) {
                    const int R = (g << 6) + (wc << 5) + (nf << 4) + (lane & 15);
                    const int sl = (((kk << 2) | (lane >> 4)) ^ (R & 7)) << 3;
                    bw[g][nf] = *(const bf16x8*)&Ws[buf][(R << 6) + sl];
                }
            #pragma unroll
            for (int mf = 0; mf < 2; ++mf)
                #pragma unroll
                for (int nf = 0; nf < 2; ++nf) {
                    tr[mf][nf] = __builtin_amdgcn_mfma_f32_16x16x32_bf16(af[mf], bw[0][nf], tr[mf][nf], 0, 0, 0);
                    tz[mf][nf] = __builtin_amdgcn_mfma_f32_16x16x32_bf16(af[mf], bw[1][nf], tz[mf][nf], 0, 0, 0);
                    tn[mf][nf] = __builtin_amdgcn_mfma_f32_16x16x32_bf16(af[mf], bw[2][nf], tn[mf][nf], 0, 0, 0);
                }
        }
    };

    stage(0, 0);
    #pragma unroll
    for (int s = 0; s < 14; ++s) {
        __syncthreads();
        if (s + 1 < 14) stage((s + 1) & 1, s + 1);
        if (s < 12)       compute(s & 1, a_sr, a_sz, a_snh);
        else if (s == 12) compute(s & 1, a_sr, a_sz, a_snx);
        else              compute(s & 1, a_ar, a_az, a_an);
    }

    #pragma unroll
    for (int nf = 0; nf < 2; ++nf) {
        const int jc = col0 + (wc << 5) + (nf << 4) + (lane & 15);
        const float bsr  = gs_bx[jc] + gs_bh[jc];
        const float bsz  = gs_bx[256 + jc] + gs_bh[256 + jc];
        const float bsnx = gs_bx[512 + jc];
        const float bsnh = gs_bh[512 + jc];
        const float bar_ = ga_bx[jc];
        const float baz  = ga_bx[256 + jc];
        const float ban  = ga_bx[512 + jc];
        #pragma unroll
        for (int mf = 0; mf < 2; ++mf) {
            #pragma unroll
            for (int r = 0; r < 4; ++r) {
                const int rowl = (wr << 5) + (mf << 4) + ((lane >> 4) << 2) + r;
                const int m = m0 + rowl;
                const int b = m & 1023;
                // fraternal GRU
                const float rs = sigmf(a_sr[mf][nf][r] + bsr);
                const float zs = sigmf(a_sz[mf][nf][r] + bsz);
                const float ns = tanhf(a_snx[mf][nf][r] + bsnx + rs * (a_snh[mf][nf][r] + bsnh));
                const size_t hrow = aBase + rowl;
                const float hv = bf2f(Hn2[hrow * 512 + jc]) + bf2f(Hn2[hrow * 512 + 256 + jc]);
                const float hf = (1.f - zs) * ns + zs * hv;
                // ancestral GRU (h-parts from GhA = hac@wh^T + bh)
                const float ghr = GhA[(size_t)b * 768 + jc];
                const float ghz = GhA[(size_t)b * 768 + 256 + jc];
                const float ghn = GhA[(size_t)b * 768 + 512 + jc];
                const float ra = sigmf(a_ar[mf][nf][r] + bar_ + ghr);
                const float za = sigmf(a_az[mf][nf][r] + baz + ghz);
                const float na = tanhf(a_an[mf][nf][r] + ban + ra * ghn);
                const float ap = (1.f - za) * na + za * haF[(size_t)b * 256 + jc];
                // hidden2
                const float val = hf + ap;
                const unsigned short hi = f2bf(val);
                Ap2[(size_t)m * 512 + jc] = hi;
                Ap2[(size_t)m * 512 + 256 + jc] = f2bf(val - bf2f(hi));
            }
        }
    }
}

// ---------------------------------------------------------------------------
extern "C" void kernel_launch(void* const* d_in, const int* in_sizes, int n_in,
                              void* d_out, int out_size, void* d_ws, size_t ws_size,
                              hipStream_t stream) {
    (void)in_sizes; (void)n_in; (void)out_size;

    const float* z      = (const float*)d_in[0];
    const float* h2o_w  = (const float*)d_in[1];
    const float* h2o_b  = (const float*)d_in[2];
    const float* w_c_w  = (const float*)d_in[3];
    const float* w_c_b  = (const float*)d_in[4];
    const float* w_d_w  = (const float*)d_in[5];
    const float* w_d_b  = (const float*)d_in[6];
    const float* z2h1_w = (const float*)d_in[7];
    const float* z2h1_b = (const float*)d_in[8];
    const float* z2h2_w = (const float*)d_in[9];
    const float* z2h2_b = (const float*)d_in[10];
    const float* ga_wx  = (const float*)d_in[11];
    const float* ga_wh  = (const float*)d_in[12];
    const float* ga_bx  = (const float*)d_in[13];
    const float* ga_bh  = (const float*)d_in[14];
    const float* gs_wx  = (const float*)d_in[15];
    const float* gs_wh  = (const float*)d_in[16];
    const float* gs_bx  = (const float*)d_in[17];
    const float* gs_bh  = (const float*)d_in[18];

    float* out = (float*)d_out;

    size_t off = 0;
    auto alloc = [&](size_t bytes) -> void* {
        void* r = (char*)d_ws + off;
        off += (bytes + 255) & ~(size_t)255;
        return r;
    };
    unsigned short* H2a  = (unsigned short*)alloc(16ull * 1024 * 512 * 2);
    unsigned short* H2b  = (unsigned short*)alloc(32ull * 1024 * 512 * 2);
    unsigned short* SP2a = (unsigned short*)alloc(16ull * 1024 * 64 * 2);
    unsigned short* SP2b = (unsigned short*)alloc(32ull * 1024 * 64 * 2);
    float* hacF0 = (float*)alloc(1024ull * 256 * 4);
    float* hacF1 = (float*)alloc(1024ull * 256 * 4);
    unsigned short* hac20 = (unsigned short*)alloc(1024ull * 512 * 2);
    unsigned short* hac21 = (unsigned short*)alloc(1024ull * 512 * 2);
    float* GhA = (float*)alloc(1024ull * 768 * 4);
    unsigned short* Ap2 = (unsigned short*)alloc(16ull * 1024 * 512 * 2);
    unsigned short* z2  = (unsigned short*)alloc(1024ull * 512 * 2);
    unsigned short* wd2 = (unsigned short*)alloc(256ull * 512 * 2);
    unsigned short* wcat = (unsigned short*)alloc(1024ull * 512 * 2);  // [ga_wh(768) | w_c_w(256)]
    unsigned short* gaW2 = wcat;
    unsigned short* wc2  = wcat + 768ull * 512;
    unsigned short* z12 = (unsigned short*)alloc(256ull * 512 * 2);
    unsigned short* z22 = (unsigned short*)alloc(256ull * 512 * 2);
    unsigned short* gsW2 = (unsigned short*)alloc(768ull * 512 * 2);
    unsigned short* gsX2 = (unsigned short*)alloc(768ull * 64 * 2);
    unsigned short* gaX2 = (unsigned short*)alloc(768ull * 64 * 2);
    unsigned short* h2o2 = (unsigned short*)alloc(32ull * 512 * 2);
    if (off > ws_size) return;  // tripwire

    const dim3 blk(256);

    CvtArgs ca = {{
        { z,      z2,   1024 * 256, 8 },
        { w_d_w,  wd2,  256 * 256,  8 },
        { w_c_w,  wc2,  256 * 256,  8 },
        { z2h1_w, z12,  256 * 256,  8 },
        { z2h2_w, z22,  256 * 256,  8 },
        { ga_wh,  gaW2, 768 * 256,  8 },
        { gs_wh,  gsW2, 768 * 256,  8 },
        { gs_wx,  gsX2, 768 * 32,   5 },
        { ga_wx,  gaX2, 768 * 32,   5 },
        { h2o_w,  h2o2, 32 * 256,   8 },
    }};
    cvt_bf16x2<<<dim3(64, 10), blk, 0, stream>>>(ca);

    // init: hac = z@z2h1^T+b ; H(root) = z@z2h2^T+b ; root pred+softmax
    mfma_gemm<<<dim3(2, 8), blk, 0, stream>>>(z2, z12, z2h1_b, hacF0, 256, hac20, 1, 0);
    mfma_gemm<<<dim3(2, 8), blk, 0, stream>>>(z2, z22, z2h2_b, nullptr, 0, H2a, 1, 0);
    pred_softmax_mfma<<<dim3(8), blk, 0, stream>>>(H2a, h2o2, h2o_b, out, SP2a, 0, 1, 0);

    unsigned short* cur2 = H2a;  unsigned short* nxt2 = H2b;
    unsigned short* spc  = SP2a; unsigned short* spn  = SP2b;
    float* hf = hacF0;  float* hn = hacF1;
    unsigned short* hf2 = hac20; unsigned short* hn2 = hac21;

    for (int l = 0; l < DEPTHC - 1; ++l) {
        const int M = (1 << l) * Bdim;

        // first children: H' = lin_d(H) -> slots 2p
        mfma_gemm<<<dim3(2, M / 128), blk, 0, stream>>>(cur2, wd2, w_d_b, nullptr, 0, nxt2, 2, 0);
        // pred + softmax of first children
        pred_softmax_mfma<<<dim3(M / 128), blk, 0, stream>>>(nxt2, h2o2, h2o_b, out, spn, l + 1, 2, 0);
        // GhA = hac@ga_wh^T + ga_bh  AND  hac' = lin_c(hac), one dual dispatch
        mfma_gemm_dual<<<dim3(8, 8), blk, 0, stream>>>(hf2, wcat, ga_bh, w_c_b, GhA, hn, hn2);
        // fused fraternal+ancestral GRU -> hidden2 (bf16x2) in Ap2
        gru_s_fused<<<dim3(4, M / 64), blk, 0, stream>>>(
            nxt2, spn, spc, gsW2, gsX2, gaX2, gs_bx, gs_bh, ga_bx, GhA, hf, Ap2);
        // second children: H'' = lin_d(hidden2) -> slots 2p+1
        mfma_gemm<<<dim3(2, M / 128), blk, 0, stream>>>(Ap2, wd2, w_d_b, nullptr, 0, nxt2, 2, 1);
        // pred + softmax of second children
        pred_softmax_mfma<<<dim3(M / 128), blk, 0, stream>>>(nxt2, h2o2, h2o_b, out, spn, l + 1, 2, 1);

        // swap ping-pong buffers
        unsigned short* t2;
        t2 = cur2; cur2 = nxt2; nxt2 = t2;
        t2 = spc;  spc  = spn;  spn  = t2;
        float* tf = hf; hf = hn; hn = tf;
        t2 = hf2; hf2 = hn2; hn2 = t2;
    }
}